// Round 8
// baseline (864.154 us; speedup 1.0000x reference)
//
#include <hip/hip_runtime.h>
#include <hip/hip_bf16.h>

// LSTM B=256 T=512 H=256 E=6 V=10 C=10. fp32 in/out.
// ROUND 23: DUAL-RECURRENCE PIPELINE. r22 = 476us = 2230cy/step vs 1307cy
// matrix floor (64 i8-MFMA/SIMD x 20.4cy, m16 ubench); ~920cy of elem/
// barrier/DS tail exposed per step, and r16/r19/r20/r21 showed cross-wave
// overlap can't reclaim it (lockstep attractor; +3% max from setprio).
// This round: batch columns are INDEPENDENT recurrences -> each block owns
// TWO column-pairs (4 cols, 64 blocks). Per iteration (= 1 step for both
// pairs): read hfA -> issue 32 MFMA_A -> read hfB -> issue 32 MFMA_B ->
// elem_A (VALU overlaps matrix pipe executing B's queue - AITER-style
// intra-wave MFMA/VALU overlap) -> elem_B -> ONE barrier (covers 2
// col-steps). Matrix window/iter 2614cy swallows elem_A + DS; exposed =
// elem_B + barrier (~350cy). Model: ~1500cy/col-step vs 2230.
// Bit-exactness: raw x-table (40KB, col-independent) + per-col bias regs;
// elem computes (ts+b)*K with r20-validated op order == r22's precomputed
// tb. i32 MFMA accumulation order unchanged. absmax must stay 0.0078125.
// Kept: INT8 MFMA 16x16x64, reg-resident per-row-quantized weights
// (wa[2][4][4]=128 VGPR), h @127 double-buffered LDS (320B/col stride),
// pre-scaled u16 digit offsets (1 u32 read / 2 steps / pair), unroll x2
// (parity addresses loop-invariant), setprio skew, single-rcp c-update,
// constant-index cndmask select. VGPR risk ~250/256: watch VGPR_Count.

typedef __attribute__((ext_vector_type(4))) int   int4v;
typedef __attribute__((ext_vector_type(4))) float float4v;

#define MFMA_I8(a, b, c) __builtin_amdgcn_mfma_i32_16x16x64_i8(a, b, c, 0, 0, 0)

#define K_TANH (-2.8853900817779268f)   // exp2(K_TANH*x) = e^(-2x)
#define K_SIG  (-1.4426950408889634f)   // exp2(K_SIG*x)  = e^(-x)

#define HS 320                          // bytes per col in hbuf (80 dw == 16 mod 32)

__device__ __forceinline__ short f2b(float f) {
    __hip_bfloat16 b = __float2bfloat16(f); return *(short*)&b;
}
__device__ __forceinline__ float b2f(short s) {
    union { unsigned int u; float f; } v; v.u = ((unsigned int)(unsigned short)s) << 16; return v.f;
}
__device__ __forceinline__ float fexp2(float x) {
#if __has_builtin(__builtin_amdgcn_exp2f)
    return __builtin_amdgcn_exp2f(x);
#else
    return __expf(x * 0.6931471805599453f);
#endif
}
__device__ __forceinline__ float frcp(float x) { return __builtin_amdgcn_rcpf(x); }

__global__ __attribute__((amdgpu_flat_work_group_size(512, 512), amdgpu_waves_per_eu(2, 2)))
void lstm_i8(
    const int* __restrict__ x,
    const float* __restrict__ emb,
    const float* __restrict__ Wxg, const float* __restrict__ Whg, const float* __restrict__ bg,
    const float* __restrict__ Wxi, const float* __restrict__ Whi, const float* __restrict__ bi,
    const float* __restrict__ Wxf, const float* __restrict__ Whf, const float* __restrict__ bff,
    const float* __restrict__ Wxo, const float* __restrict__ Who, const float* __restrict__ bo,
    const float* __restrict__ Wp, const float* __restrict__ bp,
    float* __restrict__ out)
{
    const int tid = threadIdx.x, bid = blockIdx.x;
    const int c0 = bid * 4;                 // 4 batch columns per block (2 pairs)
    const int w = tid >> 6, lane = tid & 63;
    const int l = lane & 15, q = lane >> 4;
    const int colb = lane & 1;              // column parity within a pair
    const int rtb = (lane >> 1) & 1;        // row-tile select bit
    const int si  = (lane >> 2) & 3;        // acc reg index
    const int rwb = 32 * w;                 // this wave's 32-row base
    const int row = rwb + 16 * rtb + 4 * q + si;   // this thread's hidden row

    __shared__ __align__(16) char hbuf[2][4 * HS];     // h i8 [parity][col][k], cols 0..3
    __shared__ __align__(16) short hfin[4 * 264];      // final h bf16 [col][k]
    __shared__ __align__(4) unsigned short xoff[4][512];  // [col][t] = digit<<12
    __shared__ __align__(16) float tblS[10 * 1024];    // [d][r][4g] RAW x-path (no bias/K)
    __shared__ float scaleL[4 * 256];                  // per-gate per-row max|W|

    const float* WxT[4] = {Wxg, Wxi, Wxf, Wxo};
    const float* WhT[4] = {Whg, Whi, Whf, Who};
    const float* bT[4]  = {bg, bi, bff, bo};

    // ---- init: zero h buf0 (both pairs), stage pre-scaled digit offsets ----
    if (tid < 4 * HS / 4) ((unsigned int*)hbuf[0])[tid] = 0u;
    for (int i = tid; i < 2048; i += 512) {
        int cc = i >> 9, t = i & 511;
        xoff[cc][t] = (unsigned short)(x[(c0 + cc) * 512 + t] << 12);
    }

    // ---- RAW x-path table (col-independent): tblS[d][r][g] = Wx[g]row . emb[d] ----
    for (int i = tid; i < 2560; i += 512) {
        int d = i >> 8, r = i & 255;
        float4v v;
        #pragma unroll
        for (int g = 0; g < 4; g++) {
            float s = 0.f;
            #pragma unroll
            for (int e = 0; e < 6; e++) s += WxT[g][r * 6 + e] * emb[d * 6 + e];
            v[g] = s;
        }
        *(float4v*)&tblS[d * 1024 + r * 4] = v;
    }

    // ---- weight quantization: per-row scale, i8 A-frags in registers ----
    int4v wa[2][4][4];
    #pragma unroll
    for (int rt = 0; rt < 2; rt++) {
        #pragma unroll
        for (int g = 0; g < 4; g++) {
            const float* Wr = WhT[g] + (rwb + rt * 16 + l) * 256 + q * 16;
            float mx = 0.f;
            #pragma unroll
            for (int kt = 0; kt < 4; kt++)
                #pragma unroll
                for (int c4 = 0; c4 < 4; c4++) {
                    float4v v = *(const float4v*)(Wr + kt * 64 + c4 * 4);
                    #pragma unroll
                    for (int j = 0; j < 4; j++) mx = fmaxf(mx, fabsf(v[j]));
                }
            mx = fmaxf(mx, __shfl_xor(mx, 16));
            mx = fmaxf(mx, __shfl_xor(mx, 32));
            mx = fmaxf(mx, 1e-20f);
            if (q == 0) scaleL[g * 256 + rwb + rt * 16 + l] = mx;
            float qs = 127.f / mx;
            #pragma unroll
            for (int kt = 0; kt < 4; kt++) {
                int4v f;
                #pragma unroll
                for (int dw = 0; dw < 4; dw++) {
                    float4v v = *(const float4v*)(Wr + kt * 64 + dw * 4);
                    int word = 0;
                    #pragma unroll
                    for (int byt = 0; byt < 4; byt++) {
                        int z = (int)rintf(v[byt] * qs);
                        word |= (z & 255) << (8 * byt);
                    }
                    f[dw] = word;
                }
                wa[rt][g][kt] = f;
            }
        }
    }

    __syncthreads();   // scaleL/tblS/xoff/hbuf[0] visible

    if ((w & 1) == 0) __builtin_amdgcn_s_setprio(1);   // r21 skew (+3%)

    // ---- loop-invariants ----
    float dscl[4];
    #pragma unroll
    for (int g = 0; g < 4; g++) {
        float kk = (g == 0 ? K_TANH : K_SIG) * (1.f / 16129.f);   // 127^2
        dscl[g] = scaleL[g * 256 + row] * kk;
    }
    float brvA[4], brvB[4];
    #pragma unroll
    for (int g = 0; g < 4; g++) {
        brvA[g] = bT[g][c0 + colb];
        brvB[g] = bT[g][c0 + 2 + colb];
    }

    const bool bi1 = (si & 1) != 0;
    const bool bi2 = (si & 2) != 0;
    const bool brt = rtb != 0;
    const char* tprowB = (const char*)tblS + row * 16;   // + digit<<12 at runtime

    // loop-invariant h addresses (both parities, both pairs)
    const char* rA0 = hbuf[0] + colb * HS + q * 16;   // pair A reads, parity 0
    const char* rA1 = hbuf[1] + colb * HS + q * 16;
    const char* rB0 = rA0 + 2 * HS;                   // pair B reads
    const char* rB1 = rA1 + 2 * HS;
    char* wA0 = hbuf[0] + colb * HS + row;            // pair A writes (into parity 0)
    char* wA1 = hbuf[1] + colb * HS + row;
    char* wB0 = wA0 + 2 * HS;
    char* wB1 = wA1 + 2 * HS;
    const char* xobA = (const char*)&xoff[colb][0];
    const char* xobB = (const char*)&xoff[2 + colb][0];

    const int4v Z = {0, 0, 0, 0};

    float csA = 0.f, hlA = 0.f, csB = 0.f, hlB = 0.f;

    unsigned int oA = *(const unsigned int*)(xobA);   // digit offsets steps (0,1)
    unsigned int oB = *(const unsigned int*)(xobB);

// 32 MFMAs: 8 independent chains (2 row-tiles x 4 gates) x 4 k-tiles
#define MFMA32(H0, H1, H2, H3, g0, g1, i0, i1, f0, f1, o0, o1)  \
    g0 = MFMA_I8(wa[0][0][0], H0, Z); g1 = MFMA_I8(wa[1][0][0], H0, Z); \
    i0 = MFMA_I8(wa[0][1][0], H0, Z); i1 = MFMA_I8(wa[1][1][0], H0, Z); \
    f0 = MFMA_I8(wa[0][2][0], H0, Z); f1 = MFMA_I8(wa[1][2][0], H0, Z); \
    o0 = MFMA_I8(wa[0][3][0], H0, Z); o1 = MFMA_I8(wa[1][3][0], H0, Z); \
    g0 = MFMA_I8(wa[0][0][1], H1, g0); g1 = MFMA_I8(wa[1][0][1], H1, g1); \
    i0 = MFMA_I8(wa[0][1][1], H1, i0); i1 = MFMA_I8(wa[1][1][1], H1, i1); \
    f0 = MFMA_I8(wa[0][2][1], H1, f0); f1 = MFMA_I8(wa[1][2][1], H1, f1); \
    o0 = MFMA_I8(wa[0][3][1], H1, o0); o1 = MFMA_I8(wa[1][3][1], H1, o1); \
    g0 = MFMA_I8(wa[0][0][2], H2, g0); g1 = MFMA_I8(wa[1][0][2], H2, g1); \
    i0 = MFMA_I8(wa[0][1][2], H2, i0); i1 = MFMA_I8(wa[1][1][2], H2, i1); \
    f0 = MFMA_I8(wa[0][2][2], H2, f0); f1 = MFMA_I8(wa[1][2][2], H2, f1); \
    o0 = MFMA_I8(wa[0][3][2], H2, o0); o1 = MFMA_I8(wa[1][3][2], H2, o1); \
    g0 = MFMA_I8(wa[0][0][3], H3, g0); g1 = MFMA_I8(wa[1][0][3], H3, g1); \
    i0 = MFMA_I8(wa[0][1][3], H3, i0); i1 = MFMA_I8(wa[1][1][3], H3, i1); \
    f0 = MFMA_I8(wa[0][2][3], H3, f0); f1 = MFMA_I8(wa[1][2][3], H3, f1); \
    o0 = MFMA_I8(wa[0][3][3], H3, o0); o1 = MFMA_I8(wa[1][3][3], H3, o1);

// elem for one (row,col) element: selects, gates, c/h update, quantized write
#define ELEM(G0, G1, I0, I1, F0, F1, O0, O1, TS, BRV, CS, HL, WP)  \
    { \
        int avg_, avi_, avf_, avo_; \
        { int t0 = bi1 ? G0[1] : G0[0]; int t1 = bi1 ? G0[3] : G0[2]; int s0 = bi2 ? t1 : t0; \
          int u0 = bi1 ? G1[1] : G1[0]; int u1 = bi1 ? G1[3] : G1[2]; int s1 = bi2 ? u1 : u0; \
          avg_ = brt ? s1 : s0; } \
        { int t0 = bi1 ? I0[1] : I0[0]; int t1 = bi1 ? I0[3] : I0[2]; int s0 = bi2 ? t1 : t0; \
          int u0 = bi1 ? I1[1] : I1[0]; int u1 = bi1 ? I1[3] : I1[2]; int s1 = bi2 ? u1 : u0; \
          avi_ = brt ? s1 : s0; } \
        { int t0 = bi1 ? F0[1] : F0[0]; int t1 = bi1 ? F0[3] : F0[2]; int s0 = bi2 ? t1 : t0; \
          int u0 = bi1 ? F1[1] : F1[0]; int u1 = bi1 ? F1[3] : F1[2]; int s1 = bi2 ? u1 : u0; \
          avf_ = brt ? s1 : s0; } \
        { int t0 = bi1 ? O0[1] : O0[0]; int t1 = bi1 ? O0[3] : O0[2]; int s0 = bi2 ? t1 : t0; \
          int u0 = bi1 ? O1[1] : O1[0]; int u1 = bi1 ? O1[3] : O1[2]; int s1 = bi2 ? u1 : u0; \
          avo_ = brt ? s1 : s0; } \
        float pg = fmaf((float)avg_, dscl[0], (TS[0] + BRV[0]) * K_TANH); \
        float Eg = fexp2(pg); \
        float pi = fmaf((float)avi_, dscl[1], (TS[1] + BRV[1]) * K_SIG); \
        float Ei = fexp2(pi); \
        float m1 = (1.f + Eg) * (1.f + Ei); \
        float pf = fmaf((float)avf_, dscl[2], (TS[2] + BRV[2]) * K_SIG); \
        float Ef = fexp2(pf); \
        float fp1 = 1.f + Ef; \
        float num = fmaf(CS, m1, (1.f - Eg) * fp1); \
        float c = num * frcp(m1 * fp1); \
        CS = c; \
        float Ec = fexp2(K_TANH * c); \
        float po = fmaf((float)avo_, dscl[3], (TS[3] + BRV[3]) * K_SIG); \
        float Eo = fexp2(po); \
        float hh = (1.f - Ec) * frcp((1.f + Ec) * (1.f + Eo)); \
        HL = hh; \
        *(WP) = (char)((int)rintf(hh * 127.f)); \
    }

// one iteration step for both pairs; PRE = offset prefetch (even substep only)
#define SUBD(RA, RB, WA, WB, OFA, OFB, PRE)  \
    { \
        int4v hA0 = *(const int4v*)((RA) + 0); \
        int4v hA1 = *(const int4v*)((RA) + 64); \
        int4v hA2 = *(const int4v*)((RA) + 128); \
        int4v hA3 = *(const int4v*)((RA) + 192); \
        int4v aAg0, aAg1, aAi0, aAi1, aAf0, aAf1, aAo0, aAo1; \
        MFMA32(hA0, hA1, hA2, hA3, aAg0, aAg1, aAi0, aAi1, aAf0, aAf1, aAo0, aAo1) \
        int4v hB0 = *(const int4v*)((RB) + 0); \
        int4v hB1 = *(const int4v*)((RB) + 64); \
        int4v hB2 = *(const int4v*)((RB) + 128); \
        int4v hB3 = *(const int4v*)((RB) + 192); \
        int4v aBg0, aBg1, aBi0, aBi1, aBf0, aBf1, aBo0, aBo1; \
        MFMA32(hB0, hB1, hB2, hB3, aBg0, aBg1, aBi0, aBi1, aBf0, aBf1, aBo0, aBo1) \
        float4v tsA = *(const float4v*)(tprowB + (OFA)); \
        float4v tsB = *(const float4v*)(tprowB + (OFB)); \
        PRE \
        ELEM(aAg0, aAg1, aAi0, aAi1, aAf0, aAf1, aAo0, aAo1, tsA, brvA, csA, hlA, WA) \
        ELEM(aBg0, aBg1, aBi0, aBi1, aBf0, aBf1, aBo0, aBo1, tsB, brvB, csB, hlB, WB) \
        __syncthreads(); \
    }

    for (int i = 0; i < 256; ++i) {
        const int t2 = i << 1;
        int tnx = t2 + 2; if (tnx > 510) tnx = 510;   // uniform clamp (last iter dummy)
        unsigned int dnA, dnB;
        // even step: parity 0 -> 1; uses low-half offsets; prefetch next u32 pair
        SUBD(rA0, rB0, wA1, wB1, (oA & 0xFFFFu), (oB & 0xFFFFu),
             dnA = *(const unsigned int*)(xobA + tnx * 2);
             dnB = *(const unsigned int*)(xobB + tnx * 2);)
        // odd step: parity 1 -> 0; uses high-half offsets
        SUBD(rA1, rB1, wA0, wB0, (oA >> 16), (oB >> 16), ;)
        oA = dnA; oB = dnB;
    }
#undef SUBD
#undef ELEM
#undef MFMA32

    if ((w & 1) == 0) __builtin_amdgcn_s_setprio(0);

    // ---- stage final h (exact f32->bf16) for projection ----
    hfin[colb * 264 + row]       = f2b(hlA);
    hfin[(2 + colb) * 264 + row] = f2b(hlB);
    __syncthreads();

    // ---- projection: out[c0+pc][cls] = Wp[cls] . h_final + bp[cls] ----
    if (tid < 40) {
        int pc = tid / 10, cls = tid - pc * 10;
        const short* hcol = &hfin[pc * 264];
        const float* wrow = Wp + cls * 256;
        float s = 0.f;
        #pragma unroll 8
        for (int k = 0; k < 256; k++) s += b2f(hcol[k]) * wrow[k];
        out[(c0 + pc) * 10 + cls] = s + bp[cls];
    }
}

extern "C" void kernel_launch(void* const* d_in, const int* in_sizes, int n_in,
                              void* d_out, int out_size, void* d_ws, size_t ws_size,
                              hipStream_t stream) {
    const int*   x   = (const int*)d_in[0];
    const float* emb = (const float*)d_in[1];
    const float* Wxg = (const float*)d_in[2];
    const float* Whg = (const float*)d_in[3];
    const float* bg  = (const float*)d_in[4];
    const float* Wxi = (const float*)d_in[5];
    const float* Whi = (const float*)d_in[6];
    const float* bi  = (const float*)d_in[7];
    const float* Wxf = (const float*)d_in[8];
    const float* Whf = (const float*)d_in[9];
    const float* bff = (const float*)d_in[10];
    const float* Wxo = (const float*)d_in[11];
    const float* Who = (const float*)d_in[12];
    const float* bo  = (const float*)d_in[13];
    const float* Wp  = (const float*)d_in[14];
    const float* bp  = (const float*)d_in[15];

    hipLaunchKernelGGL(lstm_i8, dim3(64), dim3(512), 0, stream,
                       x, emb, Wxg, Whg, bg, Wxi, Whi, bi, Wxf, Whf, bff,
                       Wxo, Who, bo, Wp, bp, (float*)d_out);
}

// Round 9
// 523.606 us; speedup vs baseline: 1.6504x; 1.6504x over previous
//
#include <hip/hip_runtime.h>
#include <hip/hip_bf16.h>

// LSTM B=256 T=512 H=256 E=6 V=10 C=10. fp32 in/out.
// ROUND 24: REVERT to r22 (verified 476us) + tblC bank-conflict stride fix.
// r23 (dual-recurrence) diagnosis: needs ~284 live regs vs the 256 unified
// VGPR+AGPR cap at 2 waves/SIMD (VGPR_Count=128 is the VGPR segment only;
// accs live in AGPRs) -> scratch spills in the serial loop -> 822us. The
// overlap-family is now closed: flags (r16,r19) regress, cross-block (r20)
// catastrophic, setprio skew (r21) +3%, dual-recurrence (r23) spills.
// This round's one change vs r22: tblC column stride 10240 -> 10244 floats
// (+16B). Old stride 40960B == 0 mod 128 -> (col0,col1) lane pairs of the
// per-step x-table ds_read_b128 hit the same banks (SQ_LDS_BANK_CONFLICT
// 6.8M ~= 104 cy/CU/step). +4 floats puts cols 4 banks apart. No semantic
// change; absmax must stay exactly 0.0078125.
// Structure (r22): 128 blocks x 512 thr (8 waves, 2/SIMD), 2 cols/block,
// INT8 MFMA 16x16x64, reg-resident per-row-quantized weights (wa[2][4][4]
// =128 VGPR), h @127 double-buffered LDS, bias folded into per-col x-table
// tblC, pre-scaled u16 digit offsets, manual unroll x2 (loop-invariant
// parity addresses), setprio skew, per-gate elem tails, single-rcp
// c-update, constant-index cndmask select.
// PRE-COMMIT: if >=465us, declare serial-sum roofline next round.

typedef __attribute__((ext_vector_type(4))) int   int4v;
typedef __attribute__((ext_vector_type(4))) float float4v;

#define MFMA_I8(a, b, c) __builtin_amdgcn_mfma_i32_16x16x64_i8(a, b, c, 0, 0, 0)

#define K_TANH (-2.8853900817779268f)   // exp2(K_TANH*x) = e^(-2x)
#define K_SIG  (-1.4426950408889634f)   // exp2(K_SIG*x)  = e^(-x)

#define HSTRIDE 320                     // bytes per col in hbuf: 80 dw == 16 mod 32
#define TCSTR 10244                     // tblC col stride (floats): 40976B == 16 mod 128
                                        // -> col0/col1 4 banks apart (was 0 -> conflict)

__device__ __forceinline__ short f2b(float f) {
    __hip_bfloat16 b = __float2bfloat16(f); return *(short*)&b;
}
__device__ __forceinline__ float b2f(short s) {
    union { unsigned int u; float f; } v; v.u = ((unsigned int)(unsigned short)s) << 16; return v.f;
}
__device__ __forceinline__ float fexp2(float x) {
#if __has_builtin(__builtin_amdgcn_exp2f)
    return __builtin_amdgcn_exp2f(x);
#else
    return __expf(x * 0.6931471805599453f);
#endif
}
__device__ __forceinline__ float frcp(float x) { return __builtin_amdgcn_rcpf(x); }

__global__ __attribute__((amdgpu_flat_work_group_size(512, 512), amdgpu_waves_per_eu(2, 2)))
void lstm_i8(
    const int* __restrict__ x,
    const float* __restrict__ emb,
    const float* __restrict__ Wxg, const float* __restrict__ Whg, const float* __restrict__ bg,
    const float* __restrict__ Wxi, const float* __restrict__ Whi, const float* __restrict__ bi,
    const float* __restrict__ Wxf, const float* __restrict__ Whf, const float* __restrict__ bff,
    const float* __restrict__ Wxo, const float* __restrict__ Who, const float* __restrict__ bo,
    const float* __restrict__ Wp, const float* __restrict__ bp,
    float* __restrict__ out)
{
    const int tid = threadIdx.x, bid = blockIdx.x;
    const int c0 = bid * 2;                 // 2 batch columns per block
    const int w = tid >> 6, lane = tid & 63;
    const int l = lane & 15, q = lane >> 4;
    const int col = lane & 1;               // this thread's column (B n-parity)
    const int rtb = (lane >> 1) & 1;        // row-tile select bit
    const int si  = (lane >> 2) & 3;        // acc reg index
    const int rwb = 32 * w;                 // this wave's 32-row base
    const int row = rwb + 16 * rtb + 4 * q + si;   // this thread's hidden row

    __shared__ __align__(16) unsigned int hbuf[2][2 * HSTRIDE / 4];  // h i8 [parity][col][k]
    __shared__ __align__(16) short hfin[2 * 264];                    // final h bf16 [col][k]
    __shared__ __align__(4) unsigned short xoff[2][512];             // [col][t] = digit<<12
    __shared__ __align__(16) float tblC[2 * TCSTR];                  // [col][d][row][4g], bias folded
    __shared__ float scaleL[4 * 256];                                // per-gate per-row max|W|

    const float* WxT[4] = {Wxg, Wxi, Wxf, Wxo};
    const float* WhT[4] = {Whg, Whi, Whf, Who};
    const float* bT[4]  = {bg, bi, bff, bo};

    // ---- init: zero h buf0, stage pre-scaled digit offsets ----
    if (tid < 2 * HSTRIDE / 4) hbuf[0][tid] = 0u;
    for (int i = tid; i < 1024; i += 512) {
        int cc = i >> 9, t = i & 511;
        xoff[cc][t] = (unsigned short)(x[(c0 + cc) * 512 + t] << 12);
    }

    // ---- x-path table per col, bias + gate-scale folded: tblC[c][d][r][g] ----
    // 5120 float4 entries = 2 cols x 10 digits x 256 rows (2560 per col)
    for (int i = tid; i < 5120; i += 512) {
        int cc  = i / 2560;                   // 0 or 1
        int rem = i - cc * 2560;              // [0,2560)
        int d = rem >> 8, r = rem & 255;      // d in [0,10), consecutive lanes -> consecutive r
        float4v v;
        #pragma unroll
        for (int g = 0; g < 4; g++) {
            float s = 0.f;
            #pragma unroll
            for (int e = 0; e < 6; e++) s += WxT[g][r * 6 + e] * emb[d * 6 + e];
            v[g] = (s + bT[g][c0 + cc]) * (g == 0 ? K_TANH : K_SIG);
        }
        *(float4v*)&tblC[cc * TCSTR + d * 1024 + r * 4] = v;
    }

    // ---- weight quantization: per-row scale, i8 A-frags in registers ----
    // Per row-tile rt (rows rwb+16rt .. +15): A[m=l -> row rwb+16rt+l]
    // [k = 64kt+16q+j], 16 i8 per lane per kt. wa[rt][g][kt] = 128 VGPRs.
    int4v wa[2][4][4];
    #pragma unroll
    for (int rt = 0; rt < 2; rt++) {
        #pragma unroll
        for (int g = 0; g < 4; g++) {
            const float* Wr = WhT[g] + (rwb + rt * 16 + l) * 256 + q * 16;
            float mx = 0.f;
            #pragma unroll
            for (int kt = 0; kt < 4; kt++)
                #pragma unroll
                for (int c4 = 0; c4 < 4; c4++) {
                    float4v v = *(const float4v*)(Wr + kt * 64 + c4 * 4);
                    #pragma unroll
                    for (int j = 0; j < 4; j++) mx = fmaxf(mx, fabsf(v[j]));
                }
            mx = fmaxf(mx, __shfl_xor(mx, 16));
            mx = fmaxf(mx, __shfl_xor(mx, 32));
            mx = fmaxf(mx, 1e-20f);
            if (q == 0) scaleL[g * 256 + rwb + rt * 16 + l] = mx;
            float qs = 127.f / mx;
            #pragma unroll
            for (int kt = 0; kt < 4; kt++) {
                int4v f;
                #pragma unroll
                for (int dw = 0; dw < 4; dw++) {
                    float4v v = *(const float4v*)(Wr + kt * 64 + dw * 4);
                    int word = 0;
                    #pragma unroll
                    for (int byt = 0; byt < 4; byt++) {
                        int z = (int)rintf(v[byt] * qs);
                        word |= (z & 255) << (8 * byt);
                    }
                    f[dw] = word;
                }
                wa[rt][g][kt] = f;
            }
        }
    }

    __syncthreads();   // scaleL/tblC/xoff/hbuf[0] visible

    // ---- static wave-priority skew (r21: +3%) ----
    if ((w & 1) == 0) __builtin_amdgcn_s_setprio(1);

    // ---- loop-invariant: dequant scales (this thread's row) ----
    float dscl[4];
    #pragma unroll
    for (int g = 0; g < 4; g++) {
        float kk = (g == 0 ? K_TANH : K_SIG) * (1.f / 16129.f);   // 127^2
        dscl[g] = scaleL[g * 256 + row] * kk;
    }

    const bool bi1 = (si & 1) != 0;
    const bool bi2 = (si & 2) != 0;
    const bool brt = rtb != 0;
    const char* tprowB = (const char*)(tblC + col * TCSTR + row * 4);  // + off at runtime
    const int hoff = col * HSTRIDE + row;

    // loop-invariant h addresses (both parities)
    const char* hb0 = (const char*)hbuf[0] + col * HSTRIDE + q * 16;   // reads, parity 0
    const char* hb1 = (const char*)hbuf[1] + col * HSTRIDE + q * 16;   // reads, parity 1
    char* hw0 = (char*)hbuf[0] + hoff;                                 // write target of sub1
    char* hw1 = (char*)hbuf[1] + hoff;                                 // write target of sub0
    const char* xobase = (const char*)&xoff[col][0];                   // per-lane digit-offset base

    const int4v Z = {0, 0, 0, 0};          // loop-invariant zero C-operand

    float cs = 0.f, hl = 0.f;

    // prefetch: offsets for (t=0, t=1); tb for t=0
    unsigned int o01 = *(const unsigned int*)(xobase);
    float4v tbA = *(const float4v*)(tprowB + (o01 & 0xFFFFu));
    float4v tbB;

// One sub-step: reads HB, writes HW, consumes TBUSE, prefetches TBPRE = tb(OFFEXPR)
#define SUBSTEP(HB, HW, TBUSE, TBPRE, OFFEXPR)                                              \
    {                                                                                       \
        int4v hf0 = *(const int4v*)((HB) + 0 * 64);                                         \
        int4v hf1 = *(const int4v*)((HB) + 1 * 64);                                         \
        int4v hf2 = *(const int4v*)((HB) + 2 * 64);                                         \
        int4v hf3 = *(const int4v*)((HB) + 3 * 64);                                         \
        int4v ag0 = MFMA_I8(wa[0][0][0], hf0, Z);                                           \
        int4v ag1 = MFMA_I8(wa[1][0][0], hf0, Z);                                           \
        int4v ai0 = MFMA_I8(wa[0][1][0], hf0, Z);                                           \
        int4v ai1 = MFMA_I8(wa[1][1][0], hf0, Z);                                           \
        int4v af0 = MFMA_I8(wa[0][2][0], hf0, Z);                                           \
        int4v af1 = MFMA_I8(wa[1][2][0], hf0, Z);                                           \
        int4v ao0 = MFMA_I8(wa[0][3][0], hf0, Z);                                           \
        int4v ao1 = MFMA_I8(wa[1][3][0], hf0, Z);                                           \
        ag0 = MFMA_I8(wa[0][0][1], hf1, ag0);                                               \
        ag1 = MFMA_I8(wa[1][0][1], hf1, ag1);                                               \
        ai0 = MFMA_I8(wa[0][1][1], hf1, ai0);                                               \
        ai1 = MFMA_I8(wa[1][1][1], hf1, ai1);                                               \
        af0 = MFMA_I8(wa[0][2][1], hf1, af0);                                               \
        af1 = MFMA_I8(wa[1][2][1], hf1, af1);                                               \
        ao0 = MFMA_I8(wa[0][3][1], hf1, ao0);                                               \
        ao1 = MFMA_I8(wa[1][3][1], hf1, ao1);                                               \
        ag0 = MFMA_I8(wa[0][0][2], hf2, ag0);                                               \
        ag1 = MFMA_I8(wa[1][0][2], hf2, ag1);                                               \
        ai0 = MFMA_I8(wa[0][1][2], hf2, ai0);                                               \
        ai1 = MFMA_I8(wa[1][1][2], hf2, ai1);                                               \
        af0 = MFMA_I8(wa[0][2][2], hf2, af0);                                               \
        af1 = MFMA_I8(wa[1][2][2], hf2, af1);                                               \
        ao0 = MFMA_I8(wa[0][3][2], hf2, ao0);                                               \
        ao1 = MFMA_I8(wa[1][3][2], hf2, ao1);                                               \
        TBPRE = *(const float4v*)(tprowB + (OFFEXPR));                                      \
        ag0 = MFMA_I8(wa[0][0][3], hf3, ag0);                                               \
        ag1 = MFMA_I8(wa[1][0][3], hf3, ag1);                                               \
        int avg_;                                                                           \
        { int t0 = bi1 ? ag0[1] : ag0[0]; int t1 = bi1 ? ag0[3] : ag0[2]; int s0 = bi2 ? t1 : t0; \
          int u0 = bi1 ? ag1[1] : ag1[0]; int u1 = bi1 ? ag1[3] : ag1[2]; int s1 = bi2 ? u1 : u0; \
          avg_ = brt ? s1 : s0; }                                                           \
        float pg = fmaf((float)avg_, dscl[0], (TBUSE)[0]);                                  \
        float Eg = fexp2(pg);                                                               \
        ai0 = MFMA_I8(wa[0][1][3], hf3, ai0);                                               \
        ai1 = MFMA_I8(wa[1][1][3], hf3, ai1);                                               \
        int avi_;                                                                           \
        { int t0 = bi1 ? ai0[1] : ai0[0]; int t1 = bi1 ? ai0[3] : ai0[2]; int s0 = bi2 ? t1 : t0; \
          int u0 = bi1 ? ai1[1] : ai1[0]; int u1 = bi1 ? ai1[3] : ai1[2]; int s1 = bi2 ? u1 : u0; \
          avi_ = brt ? s1 : s0; }                                                           \
        float pi = fmaf((float)avi_, dscl[1], (TBUSE)[1]);                                  \
        float Ei = fexp2(pi);                                                               \
        float m1 = (1.f + Eg) * (1.f + Ei);                                                 \
        af0 = MFMA_I8(wa[0][2][3], hf3, af0);                                               \
        af1 = MFMA_I8(wa[1][2][3], hf3, af1);                                               \
        int avf_;                                                                           \
        { int t0 = bi1 ? af0[1] : af0[0]; int t1 = bi1 ? af0[3] : af0[2]; int s0 = bi2 ? t1 : t0; \
          int u0 = bi1 ? af1[1] : af1[0]; int u1 = bi1 ? af1[3] : af1[2]; int s1 = bi2 ? u1 : u0; \
          avf_ = brt ? s1 : s0; }                                                           \
        float pf = fmaf((float)avf_, dscl[2], (TBUSE)[2]);                                  \
        float Ef = fexp2(pf);                                                               \
        float fp1 = 1.f + Ef;                                                               \
        float num = fmaf(cs, m1, (1.f - Eg) * fp1);                                         \
        float c   = num * frcp(m1 * fp1);                                                   \
        cs = c;                                                                             \
        float Ec = fexp2(K_TANH * c);                                                       \
        ao0 = MFMA_I8(wa[0][3][3], hf3, ao0);                                               \
        ao1 = MFMA_I8(wa[1][3][3], hf3, ao1);                                               \
        int avo_;                                                                           \
        { int t0 = bi1 ? ao0[1] : ao0[0]; int t1 = bi1 ? ao0[3] : ao0[2]; int s0 = bi2 ? t1 : t0; \
          int u0 = bi1 ? ao1[1] : ao1[0]; int u1 = bi1 ? ao1[3] : ao1[2]; int s1 = bi2 ? u1 : u0; \
          avo_ = brt ? s1 : s0; }                                                           \
        float po = fmaf((float)avo_, dscl[3], (TBUSE)[3]);                                  \
        float Eo = fexp2(po);                                                               \
        float hh = (1.f - Ec) * frcp((1.f + Ec) * (1.f + Eo));                              \
        hl = hh;                                                                            \
        *(HW) = (char)((int)rintf(hh * 127.f));                                             \
        __syncthreads();                                                                    \
    }

    for (int i = 0; i < 256; ++i) {
        const int t2 = i << 1;
        int tnx = t2 + 2; if (tnx > 510) tnx = 510;     // uniform clamp (last iter dummy)
        unsigned int dn = *(const unsigned int*)(xobase + tnx * 2);   // offs (t+2, t+3)

        // sub-step t (even, parity 0): read hbuf0, write hbuf1, use tbA, prefetch tbB=tb(t+1)
        SUBSTEP(hb0, hw1, tbA, tbB, (o01 >> 16))
        // sub-step t+1 (odd, parity 1): read hbuf1, write hbuf0, use tbB, prefetch tbA=tb(t+2)
        SUBSTEP(hb1, hw0, tbB, tbA, (dn & 0xFFFFu))

        o01 = dn;
    }
#undef SUBSTEP

    if ((w & 1) == 0) __builtin_amdgcn_s_setprio(0);

    // ---- stage final h (exact f32->bf16) for projection ----
    hfin[col * 264 + row] = f2b(hl);
    __syncthreads();

    // ---- projection: out[c0+col][cls] = Wp[cls] . h_final + bp[cls] ----
    if (tid < 20) {
        int pc = tid / 10, cls = tid - pc * 10;
        const short* hcol = &hfin[pc * 264];
        const float* wrow = Wp + cls * 256;
        float s = 0.f;
        #pragma unroll 8
        for (int k = 0; k < 256; k++) s += b2f(hcol[k]) * wrow[k];
        out[(c0 + pc) * 10 + cls] = s + bp[cls];
    }
}

extern "C" void kernel_launch(void* const* d_in, const int* in_sizes, int n_in,
                              void* d_out, int out_size, void* d_ws, size_t ws_size,
                              hipStream_t stream) {
    const int*   x   = (const int*)d_in[0];
    const float* emb = (const float*)d_in[1];
    const float* Wxg = (const float*)d_in[2];
    const float* Whg = (const float*)d_in[3];
    const float* bg  = (const float*)d_in[4];
    const float* Wxi = (const float*)d_in[5];
    const float* Whi = (const float*)d_in[6];
    const float* bi  = (const float*)d_in[7];
    const float* Wxf = (const float*)d_in[8];
    const float* Whf = (const float*)d_in[9];
    const float* bff = (const float*)d_in[10];
    const float* Wxo = (const float*)d_in[11];
    const float* Who = (const float*)d_in[12];
    const float* bo  = (const float*)d_in[13];
    const float* Wp  = (const float*)d_in[14];
    const float* bp  = (const float*)d_in[15];

    hipLaunchKernelGGL(lstm_i8, dim3(128), dim3(512), 0, stream,
                       x, emb, Wxg, Whg, bg, Wxi, Whi, bi, Wxf, Whf, bff,
                       Wxo, Who, bo, Wp, bp, (float*)d_out);
}